// Round 3
// baseline (789.031 us; speedup 1.0000x reference)
//
#include <hip/hip_runtime.h>
#include <stdint.h>

// ---------------- problem constants ----------------
#define TK   8192            // tokens (B*S)
#define DD   1024            // model dim
#define EE   8               // experts
#define II   3072            // intermediate
#define TR   16384           // TK * topK
#define TRP  (TR + 128)      // padded rows (tile overrun slack)
#define MAXTILES 136
#define PERSIST_BLOCKS 512   // 2 blocks/CU x 256 CUs

typedef float  f32x4  __attribute__((ext_vector_type(4)));
typedef __bf16 bf16x8 __attribute__((ext_vector_type(8)));
typedef short  s16x8  __attribute__((ext_vector_type(8)));
typedef unsigned short u16x8 __attribute__((ext_vector_type(8)));

// ---------------- helpers ----------------
__device__ __forceinline__ unsigned short f2bf(float f) {
    union { float f; unsigned u; } v; v.f = f;
    unsigned r = v.u + 0x7fff + ((v.u >> 16) & 1);   // RNE
    return (unsigned short)(r >> 16);
}
__device__ __forceinline__ float bf2f(unsigned short b) {
    union { unsigned u; float f; } v; v.u = ((unsigned)b) << 16;
    return v.f;
}
__device__ __forceinline__ void async16(const void* g, void* l) {
    __builtin_amdgcn_global_load_lds(
        (const __attribute__((address_space(1))) unsigned int*)g,
        (__attribute__((address_space(3))) unsigned int*)l, 16, 0, 0);
}

// ---------------- ws zero init ----------------
__global__ void init_kernel(int* p) {
    int i = threadIdx.x;
#pragma unroll
    for (int j = 0; j < 4; ++j) p[j * 256 + i] = 0;
}

// ---------------- fused weight convert+transpose: all three matrices ----------------
// grid = (768, 24): y = which*8 + batch; x = flattened 64x64 tile id.
// float4 loads, ushort8 stores; LDS pad 65 keeps both phases conflict-free.
__global__ __launch_bounds__(256) void transpose_all(const float* __restrict__ w1,
                                                     const float* __restrict__ w2,
                                                     const float* __restrict__ w3,
                                                     unsigned short* __restrict__ w1t,
                                                     unsigned short* __restrict__ w2t,
                                                     unsigned short* __restrict__ w3t) {
    __shared__ float tile[64][65];
    int z = blockIdx.y;
    int which = z >> 3, b = z & 7;
    const float* src; unsigned short* dst; int R, C;
    if (which == 0)      { src = w1; dst = w1t; R = DD; C = II; }
    else if (which == 1) { src = w2; dst = w2t; R = DD; C = II; }
    else                 { src = w3; dst = w3t; R = II; C = DD; }
    int ctiles = C >> 6;
    int ct = blockIdx.x % ctiles, rt = blockIdx.x / ctiles;
    const float* s = src + (size_t)b * R * C + (size_t)(rt * 64) * C + ct * 64;
    unsigned short* d = dst + (size_t)b * R * C + (size_t)(ct * 64) * R + rt * 64;
    int tid = threadIdx.x;
#pragma unroll
    for (int k = 0; k < 4; ++k) {
        int j = tid + k * 256;                 // float4 index, 0..1023
        int r = j >> 4, c4 = j & 15;
        float4 v = *(const float4*)&s[(size_t)r * C + c4 * 4];
        tile[r][c4 * 4 + 0] = v.x; tile[r][c4 * 4 + 1] = v.y;
        tile[r][c4 * 4 + 2] = v.z; tile[r][c4 * 4 + 3] = v.w;
    }
    __syncthreads();
#pragma unroll
    for (int k = 0; k < 2; ++k) {
        int u = tid + k * 256;                 // 0..511
        int dr = u >> 3, dq = u & 7;           // dr = dst row (src col), dq*8 = src row base
        u16x8 v;
#pragma unroll
        for (int j = 0; j < 8; ++j) v[j] = f2bf(tile[dq * 8 + j][dr]);
        *(u16x8*)&d[(size_t)dr * R + dq * 8] = v;
    }
}

// ---------------- router: logits, softmax, top2, aux partials ----------------
__global__ __launch_bounds__(256) void router_kernel(const float* __restrict__ x,
                                                     const float* __restrict__ rw,
                                                     int* __restrict__ counts,
                                                     float* __restrict__ probsum,
                                                     float* __restrict__ z2sum,
                                                     int* __restrict__ tk_idx,
                                                     float* __restrict__ tk_w) {
    __shared__ float lrw[8][1024];
    __shared__ float pacc[8];
    __shared__ float zacc;
    __shared__ int   cacc[8];
    int tid = threadIdx.x;
    for (int i = tid; i < 8192; i += 256) lrw[i & 7][i >> 3] = rw[i];
    if (tid < 8) { pacc[tid] = 0.f; cacc[tid] = 0; }
    if (tid == 0) zacc = 0.f;
    __syncthreads();
    int lane = tid & 63, wv = tid >> 6;
    for (int t = blockIdx.x * 4 + wv; t < TK; t += 1024) {
        float part[8];
#pragma unroll
        for (int e = 0; e < 8; ++e) part[e] = 0.f;
        const float* xr = x + ((size_t)t << 10);
        for (int j = 0; j < 16; ++j) {
            float xv = xr[j * 64 + lane];
#pragma unroll
            for (int e = 0; e < 8; ++e) part[e] += xv * lrw[e][j * 64 + lane];
        }
#pragma unroll
        for (int e = 0; e < 8; ++e) {
            float v = part[e];
            v += __shfl_xor(v, 32); v += __shfl_xor(v, 16); v += __shfl_xor(v, 8);
            v += __shfl_xor(v, 4);  v += __shfl_xor(v, 2);  v += __shfl_xor(v, 1);
            part[e] = v;
        }
        if (lane == 0) {
            float m = part[0];
#pragma unroll
            for (int e = 1; e < 8; ++e) m = fmaxf(m, part[e]);
            float pe[8]; float se = 0.f;
#pragma unroll
            for (int e = 0; e < 8; ++e) { pe[e] = __expf(part[e] - m); se += pe[e]; }
            float inv = 1.0f / se;
            int i0 = 0; float v0 = part[0];
#pragma unroll
            for (int e = 1; e < 8; ++e) if (part[e] > v0) { v0 = part[e]; i0 = e; }
            int i1 = -1; float v1 = -1e30f;
#pragma unroll
            for (int e = 0; e < 8; ++e) if (e != i0 && part[e] > v1) { v1 = part[e]; i1 = e; }
            float p0 = pe[i0] * inv, p1 = pe[i1] * inv;
            float wn = 1.0f / (p0 + p1);
            tk_idx[t * 2 + 0] = i0; tk_idx[t * 2 + 1] = i1;
            tk_w[t * 2 + 0] = p0 * wn; tk_w[t * 2 + 1] = p1 * wn;
            float z = __logf(se) + m;
            atomicAdd(&zacc, z * z);
#pragma unroll
            for (int e = 0; e < 8; ++e) atomicAdd(&pacc[e], pe[e] * inv);
            atomicAdd(&cacc[i0], 1);
            atomicAdd(&cacc[i1], 1);
        }
    }
    __syncthreads();
    if (tid < 8) { atomicAdd(&counts[tid], cacc[tid]); atomicAdd(&probsum[tid], pacc[tid]); }
    if (tid == 0) atomicAdd(z2sum, zacc);
}

// ---------------- finalize: aux outputs, bases, tile map (parallel fill) ----------------
__global__ __launch_bounds__(256) void finalize_kernel(const int* __restrict__ counts,
                                const float* __restrict__ probsum,
                                const float* __restrict__ z2sum, int* __restrict__ base,
                                int* __restrict__ cursor, int* __restrict__ tile_e,
                                int* __restrict__ tile_r0, int* __restrict__ tile_rc,
                                int* __restrict__ num_tiles, float* __restrict__ out_aux) {
    __shared__ int scnt[8], sbase[8], tstart[9];
    int tid = threadIdx.x;
    if (tid == 0) {
        int b = 0, ts = 0; float lbl = 0.f;
        for (int e = 0; e < 8; ++e) {
            int c = counts[e];
            scnt[e] = c; sbase[e] = b; tstart[e] = ts;
            base[e] = b; cursor[e] = b;
            float load = (float)c / 16384.0f;
            out_aux[e] = load;
            lbl += (load * 4.0f) * (probsum[e] / 8192.0f);
            b += c; ts += (c + 127) >> 7;
        }
        tstart[8] = ts;
        *num_tiles = ts;
        out_aux[8] = 0.01f * lbl;
        out_aux[9] = 0.001f * (*z2sum / 8192.0f);
    }
    __syncthreads();
    int nt = tstart[8];
    for (int u = tid; u < nt; u += 256) {
        int e = 0;
#pragma unroll
        for (int k = 0; k < 8; ++k) if (u >= tstart[k + 1]) e = k + 1;
        int i = u - tstart[e];
        int rem = scnt[e] - (i << 7);
        tile_e[u] = e;
        tile_r0[u] = sbase[e] + (i << 7);
        tile_rc[u] = rem < 128 ? rem : 128;
    }
}

// ---------------- scatter: permutation via hierarchical atomics (64 blocks, 1 round) ----------------
__global__ __launch_bounds__(256) void scatter_kernel(const int* __restrict__ tk_idx,
                                                      const float* __restrict__ tk_w,
                                                      int* __restrict__ cursor,
                                                      int* __restrict__ row_token,
                                                      float* __restrict__ row_w,
                                                      int* __restrict__ pos) {
    __shared__ int hist[8];
    __shared__ int lbase[8];
    int tid = threadIdx.x;
    if (tid < 8) hist[tid] = 0;
    __syncthreads();
    int idx = blockIdx.x * 256 + tid;
    int e = tk_idx[idx];
    atomicAdd(&hist[e], 1);
    __syncthreads();
    if (tid < 8) lbase[tid] = atomicAdd(&cursor[tid], hist[tid]);
    __syncthreads();
    if (tid < 8) hist[tid] = 0;
    __syncthreads();
    int r = lbase[e] + atomicAdd(&hist[e], 1);
    row_token[r] = idx >> 1;
    row_w[r] = tk_w[idx];
    pos[idx] = r;
}

// ---------------- gather x rows -> bf16 permuted matrix ----------------
__global__ __launch_bounds__(256) void gather_kernel(const float* __restrict__ x,
                                                     const int* __restrict__ row_token,
                                                     unsigned short* __restrict__ xp) {
    int idx = blockIdx.x * 256 + threadIdx.x;      // TR*128 total
    int r = idx >> 7, j = idx & 127;
    int t = row_token[r];
    const float4* s = (const float4*)(x + ((size_t)t << 10) + (j << 3));
    float4 v0 = s[0], v1 = s[1];
    s16x8 o;
    o[0] = (short)f2bf(v0.x); o[1] = (short)f2bf(v0.y);
    o[2] = (short)f2bf(v0.z); o[3] = (short)f2bf(v0.w);
    o[4] = (short)f2bf(v1.x); o[5] = (short)f2bf(v1.y);
    o[6] = (short)f2bf(v1.z); o[7] = (short)f2bf(v1.w);
    *(s16x8*)(xp + ((size_t)r << 10) + (j << 3)) = o;
}

// ---------------- fused grouped GEMM1 (persistent): H = silu(X@W1)*(X@W2) ----------------
__global__ __launch_bounds__(256, 2) void gemm1_kernel(const short* __restrict__ Xp,
                                                       const short* __restrict__ W1t,
                                                       const short* __restrict__ W2t,
                                                       unsigned short* __restrict__ H,
                                                       const int* __restrict__ tile_e,
                                                       const int* __restrict__ tile_r0,
                                                       const int* __restrict__ tile_rc,
                                                       const int* __restrict__ num_tiles) {
    __shared__ __align__(16) short As[128 * 64];
    __shared__ __align__(16) short B1s[128 * 64];
    __shared__ __align__(16) short B2s[128 * 64];

    int tid = threadIdx.x, lane = tid & 63, wv = tid >> 6;
    int wm = wv >> 1, wn = wv & 1;
    int swz = (lane & 7) ^ ((lane >> 3) & 7);          // global chunk permutation
    short* asw = As  + wv * 32 * 64;
    short* b1w = B1s + wv * 32 * 64;
    short* b2w = B2s + wv * 32 * 64;

    int total = *num_tiles * 24;
    for (int t = blockIdx.x; t < total; t += PERSIST_BLOCKS) {
        int mt = t / 24, ntile = t - mt * 24;
        int e = tile_e[mt], m0 = tile_r0[mt], rows = tile_rc[mt];
        int n0 = ntile << 7;

        f32x4 z4 = {0.f, 0.f, 0.f, 0.f};
        f32x4 acc1[4][4], acc2[4][4];
#pragma unroll
        for (int a = 0; a < 4; ++a)
#pragma unroll
            for (int b = 0; b < 4; ++b) { acc1[a][b] = z4; acc2[a][b] = z4; }

        const short* ab  = Xp  + (size_t)(m0 + wv * 32 + (lane >> 3)) * 1024 + swz * 8;
        const short* b1b = W1t + ((size_t)e * 3072 + n0 + wv * 32 + (lane >> 3)) * 1024 + swz * 8;
        const short* b2b = W2t + ((size_t)e * 3072 + n0 + wv * 32 + (lane >> 3)) * 1024 + swz * 8;

        for (int k0 = 0; k0 < 1024; k0 += 64) {
#pragma unroll
            for (int i = 0; i < 4; ++i) {
                async16(ab  + (size_t)i * 8 * 1024 + k0, asw + i * 8 * 64);
                async16(b1b + (size_t)i * 8 * 1024 + k0, b1w + i * 8 * 64);
                async16(b2b + (size_t)i * 8 * 1024 + k0, b2w + i * 8 * 64);
            }
            __syncthreads();
#pragma unroll
            for (int kk = 0; kk < 2; ++kk) {
                bf16x8 af[4];
#pragma unroll
                for (int mi = 0; mi < 4; ++mi) {
                    int ar = wm * 64 + mi * 16 + (lane & 15);
                    int ac = (kk * 4 + (lane >> 4)) ^ (ar & 7);
                    af[mi] = *(const bf16x8*)&As[ar * 64 + ac * 8];
                }
#pragma unroll
                for (int ni = 0; ni < 4; ++ni) {
                    int br = wn * 64 + ni * 16 + (lane & 15);
                    int bc = (kk * 4 + (lane >> 4)) ^ (br & 7);
                    bf16x8 b1 = *(const bf16x8*)&B1s[br * 64 + bc * 8];
                    bf16x8 b2 = *(const bf16x8*)&B2s[br * 64 + bc * 8];
#pragma unroll
                    for (int mi = 0; mi < 4; ++mi) {
                        acc1[mi][ni] = __builtin_amdgcn_mfma_f32_16x16x32_bf16(af[mi], b1, acc1[mi][ni], 0, 0, 0);
                        acc2[mi][ni] = __builtin_amdgcn_mfma_f32_16x16x32_bf16(af[mi], b2, acc2[mi][ni], 0, 0, 0);
                    }
                }
            }
            __syncthreads();
        }
#pragma unroll
        for (int mi = 0; mi < 4; ++mi) {
#pragma unroll
            for (int i = 0; i < 4; ++i) {
                int rl = wm * 64 + mi * 16 + (lane >> 4) * 4 + i;
                if (rl < rows) {
                    size_t rowoff = (size_t)(m0 + rl) * 3072 + n0;
#pragma unroll
                    for (int ni = 0; ni < 4; ++ni) {
                        int cl = wn * 64 + ni * 16 + (lane & 15);
                        float c1 = acc1[mi][ni][i];
                        float c2 = acc2[mi][ni][i];
                        float hv = c1 * c2 / (1.0f + __expf(-c1));   // silu(c1)*c2
                        H[rowoff + cl] = f2bf(hv);
                    }
                }
            }
        }
    }
}

// ---------------- grouped GEMM2 (persistent): rows = (H @ W3) * row_w ----------------
__global__ __launch_bounds__(256, 2) void gemm2_kernel(const short* __restrict__ Hs,
                                                       const short* __restrict__ W3t,
                                                       const float* __restrict__ row_w,
                                                       unsigned short* __restrict__ OR,
                                                       const int* __restrict__ tile_e,
                                                       const int* __restrict__ tile_r0,
                                                       const int* __restrict__ tile_rc,
                                                       const int* __restrict__ num_tiles) {
    __shared__ __align__(16) short As[128 * 64];
    __shared__ __align__(16) short Bs[128 * 64];

    int tid = threadIdx.x, lane = tid & 63, wv = tid >> 6;
    int wm = wv >> 1, wn = wv & 1;
    int swz = (lane & 7) ^ ((lane >> 3) & 7);
    short* asw = As + wv * 32 * 64;
    short* bsw = Bs + wv * 32 * 64;

    int total = *num_tiles * 8;
    for (int t = blockIdx.x; t < total; t += PERSIST_BLOCKS) {
        int mt = t >> 3, ntile = t & 7;
        int e = tile_e[mt], m0 = tile_r0[mt], rows = tile_rc[mt];
        int n0 = ntile << 7;

        f32x4 z4 = {0.f, 0.f, 0.f, 0.f};
        f32x4 acc[4][4];
#pragma unroll
        for (int a = 0; a < 4; ++a)
#pragma unroll
            for (int b = 0; b < 4; ++b) acc[a][b] = z4;

        const short* ab = Hs  + (size_t)(m0 + wv * 32 + (lane >> 3)) * 3072 + swz * 8;
        const short* bb = W3t + ((size_t)e * 1024 + n0 + wv * 32 + (lane >> 3)) * 3072 + swz * 8;

        for (int k0 = 0; k0 < 3072; k0 += 64) {
#pragma unroll
            for (int i = 0; i < 4; ++i) {
                async16(ab + (size_t)i * 8 * 3072 + k0, asw + i * 8 * 64);
                async16(bb + (size_t)i * 8 * 3072 + k0, bsw + i * 8 * 64);
            }
            __syncthreads();
#pragma unroll
            for (int kk = 0; kk < 2; ++kk) {
                bf16x8 af[4];
#pragma unroll
                for (int mi = 0; mi < 4; ++mi) {
                    int ar = wm * 64 + mi * 16 + (lane & 15);
                    int ac = (kk * 4 + (lane >> 4)) ^ (ar & 7);
                    af[mi] = *(const bf16x8*)&As[ar * 64 + ac * 8];
                }
#pragma unroll
                for (int ni = 0; ni < 4; ++ni) {
                    int br = wn * 64 + ni * 16 + (lane & 15);
                    int bc = (kk * 4 + (lane >> 4)) ^ (br & 7);
                    bf16x8 bfr = *(const bf16x8*)&Bs[br * 64 + bc * 8];
#pragma unroll
                    for (int mi = 0; mi < 4; ++mi)
                        acc[mi][ni] = __builtin_amdgcn_mfma_f32_16x16x32_bf16(af[mi], bfr, acc[mi][ni], 0, 0, 0);
                }
            }
            __syncthreads();
        }
#pragma unroll
        for (int mi = 0; mi < 4; ++mi) {
#pragma unroll
            for (int i = 0; i < 4; ++i) {
                int rl = wm * 64 + mi * 16 + (lane >> 4) * 4 + i;
                if (rl < rows) {
                    float sc = row_w[m0 + rl];
                    size_t rowoff = (size_t)(m0 + rl) * 1024 + n0;
#pragma unroll
                    for (int ni = 0; ni < 4; ++ni) {
                        int cl = wn * 64 + ni * 16 + (lane & 15);
                        OR[rowoff + cl] = f2bf(acc[mi][ni][i] * sc);
                    }
                }
            }
        }
    }
}

// ---------------- combine: out[t] = rows[pos0] + rows[pos1] (already weighted) ----------------
__global__ __launch_bounds__(256) void combine_kernel(const unsigned short* __restrict__ rows,
                                                      const int* __restrict__ pos,
                                                      float* __restrict__ out) {
    int idx = blockIdx.x * 256 + threadIdx.x;      // TK*128 total
    int t = idx >> 7, j = idx & 127;
    int p0 = pos[t * 2 + 0], p1 = pos[t * 2 + 1];
    s16x8 a = *(const s16x8*)(rows + ((size_t)p0 << 10) + (j << 3));
    s16x8 b = *(const s16x8*)(rows + ((size_t)p1 << 10) + (j << 3));
    float4 o0, o1;
    o0.x = bf2f((unsigned short)a[0]) + bf2f((unsigned short)b[0]);
    o0.y = bf2f((unsigned short)a[1]) + bf2f((unsigned short)b[1]);
    o0.z = bf2f((unsigned short)a[2]) + bf2f((unsigned short)b[2]);
    o0.w = bf2f((unsigned short)a[3]) + bf2f((unsigned short)b[3]);
    o1.x = bf2f((unsigned short)a[4]) + bf2f((unsigned short)b[4]);
    o1.y = bf2f((unsigned short)a[5]) + bf2f((unsigned short)b[5]);
    o1.z = bf2f((unsigned short)a[6]) + bf2f((unsigned short)b[6]);
    o1.w = bf2f((unsigned short)a[7]) + bf2f((unsigned short)b[7]);
    float* dst = out + ((size_t)t << 10) + (j << 3);
    ((float4*)dst)[0] = o0;
    ((float4*)dst)[1] = o1;
}

// ---------------- launch ----------------
extern "C" void kernel_launch(void* const* d_in, const int* in_sizes, int n_in,
                              void* d_out, int out_size, void* d_ws, size_t ws_size,
                              hipStream_t stream) {
    const float* x  = (const float*)d_in[0];
    const float* rw = (const float*)d_in[1];
    const float* w1 = (const float*)d_in[2];
    const float* w2 = (const float*)d_in[3];
    const float* w3 = (const float*)d_in[4];
    float* out = (float*)d_out;
    char* ws = (char*)d_ws;

    // ws layout (bytes)
    int*   counts    = (int*)(ws + 0);
    int*   cursor    = (int*)(ws + 32);
    float* probsum   = (float*)(ws + 64);
    float* z2sum     = (float*)(ws + 96);
    int*   num_tiles = (int*)(ws + 100);
    int*   base      = (int*)(ws + 128);
    int*   tile_e    = (int*)(ws + 256);
    int*   tile_r0   = (int*)(ws + 1024);
    int*   tile_rc   = (int*)(ws + 1792);
    int*   row_token = (int*)(ws + 2560);
    float* row_w     = (float*)(ws + 68096);
    int*   pos       = (int*)(ws + 133632);
    int*   tk_idx    = (int*)(ws + 199168);
    float* tk_w      = (float*)(ws + 264704);
    unsigned short* xp   = (unsigned short*)(ws + 330240);     // [TRP][DD]
    unsigned short* w1t  = (unsigned short*)(ws + 34146816);   // [E][II][DD]
    unsigned short* w2t  = (unsigned short*)(ws + 84478464);
    unsigned short* w3t  = (unsigned short*)(ws + 134810112);  // [E][DD][II]
    unsigned short* h    = (unsigned short*)(ws + 185141760);  // [TRP][II]
    unsigned short* orows= (unsigned short*)(ws + 286591488);  // [TR][DD]

    init_kernel<<<dim3(1), dim3(256), 0, stream>>>((int*)ws);
    transpose_all<<<dim3(768, 24), dim3(256), 0, stream>>>(w1, w2, w3, w1t, w2t, w3t);
    router_kernel<<<dim3(256), dim3(256), 0, stream>>>(x, rw, counts, probsum, z2sum, tk_idx, tk_w);
    finalize_kernel<<<dim3(1), dim3(256), 0, stream>>>(counts, probsum, z2sum, base, cursor,
                                                       tile_e, tile_r0, tile_rc, num_tiles,
                                                       out + (size_t)TK * DD);
    scatter_kernel<<<dim3(64), dim3(256), 0, stream>>>(tk_idx, tk_w, cursor, row_token, row_w, pos);
    gather_kernel<<<dim3(TR * DD / 8 / 256), dim3(256), 0, stream>>>(x, row_token, xp);
    gemm1_kernel<<<dim3(PERSIST_BLOCKS), dim3(256), 0, stream>>>(
        (const short*)xp, (const short*)w1t, (const short*)w2t, h,
        tile_e, tile_r0, tile_rc, num_tiles);
    gemm2_kernel<<<dim3(PERSIST_BLOCKS), dim3(256), 0, stream>>>(
        (const short*)h, (const short*)w3t, row_w, orows,
        tile_e, tile_r0, tile_rc, num_tiles);
    combine_kernel<<<dim3(TK * DD / 8 / 256), dim3(256), 0, stream>>>(orows, pos, out);
}

// Round 4
// 764.167 us; speedup vs baseline: 1.0325x; 1.0325x over previous
//
#include <hip/hip_runtime.h>
#include <stdint.h>

// ---------------- problem constants ----------------
#define TK   8192            // tokens (B*S)
#define DD   1024            // model dim
#define EE   8               // experts
#define II   3072            // intermediate
#define TR   16384           // TK * topK
#define TRP  (TR + 128)      // padded rows (tile overrun slack)
#define G1_BLOCKS 768        // 3 blocks/CU (48KB LDS each, 144<=160KB)
#define G2_BLOCKS 1024       // 4 blocks/CU (32KB LDS each)

typedef float  f32x4  __attribute__((ext_vector_type(4)));
typedef __bf16 bf16x8 __attribute__((ext_vector_type(8)));
typedef short  s16x8  __attribute__((ext_vector_type(8)));
typedef unsigned short u16x8 __attribute__((ext_vector_type(8)));

// ---------------- helpers ----------------
__device__ __forceinline__ unsigned short f2bf(float f) {
    union { float f; unsigned u; } v; v.f = f;
    unsigned r = v.u + 0x7fff + ((v.u >> 16) & 1);   // RNE
    return (unsigned short)(r >> 16);
}
__device__ __forceinline__ float bf2f(unsigned short b) {
    union { unsigned u; float f; } v; v.u = ((unsigned)b) << 16;
    return v.f;
}
__device__ __forceinline__ void async16(const void* g, void* l) {
    __builtin_amdgcn_global_load_lds(
        (const __attribute__((address_space(1))) unsigned int*)g,
        (__attribute__((address_space(3))) unsigned int*)l, 16, 0, 0);
}

// ---------------- ws zero init ----------------
__global__ void init_kernel(int* p) {
    int i = threadIdx.x;
#pragma unroll
    for (int j = 0; j < 4; ++j) p[j * 256 + i] = 0;
}

// ---------------- fused weight convert+transpose: all three matrices ----------------
__global__ __launch_bounds__(256) void transpose_all(const float* __restrict__ w1,
                                                     const float* __restrict__ w2,
                                                     const float* __restrict__ w3,
                                                     unsigned short* __restrict__ w1t,
                                                     unsigned short* __restrict__ w2t,
                                                     unsigned short* __restrict__ w3t) {
    __shared__ float tile[64][65];
    int z = blockIdx.y;
    int which = z >> 3, b = z & 7;
    const float* src; unsigned short* dst; int R, C;
    if (which == 0)      { src = w1; dst = w1t; R = DD; C = II; }
    else if (which == 1) { src = w2; dst = w2t; R = DD; C = II; }
    else                 { src = w3; dst = w3t; R = II; C = DD; }
    int ctiles = C >> 6;
    int ct = blockIdx.x % ctiles, rt = blockIdx.x / ctiles;
    const float* s = src + (size_t)b * R * C + (size_t)(rt * 64) * C + ct * 64;
    unsigned short* d = dst + (size_t)b * R * C + (size_t)(ct * 64) * R + rt * 64;
    int tid = threadIdx.x;
#pragma unroll
    for (int k = 0; k < 4; ++k) {
        int j = tid + k * 256;                 // float4 index, 0..1023
        int r = j >> 4, c4 = j & 15;
        float4 v = *(const float4*)&s[(size_t)r * C + c4 * 4];
        tile[r][c4 * 4 + 0] = v.x; tile[r][c4 * 4 + 1] = v.y;
        tile[r][c4 * 4 + 2] = v.z; tile[r][c4 * 4 + 3] = v.w;
    }
    __syncthreads();
#pragma unroll
    for (int k = 0; k < 2; ++k) {
        int u = tid + k * 256;                 // 0..511
        int dr = u >> 3, dq = u & 7;
        u16x8 v;
#pragma unroll
        for (int j = 0; j < 8; ++j) v[j] = f2bf(tile[dq * 8 + j][dr]);
        *(u16x8*)&d[(size_t)dr * R + dq * 8] = v;
    }
}

// ---------------- router: logits, softmax, top2, aux partials ----------------
__global__ __launch_bounds__(256) void router_kernel(const float* __restrict__ x,
                                                     const float* __restrict__ rw,
                                                     int* __restrict__ counts,
                                                     float* __restrict__ probsum,
                                                     float* __restrict__ z2sum,
                                                     int* __restrict__ tk_idx,
                                                     float* __restrict__ tk_w) {
    __shared__ float lrw[8][1024];
    __shared__ float pacc[8];
    __shared__ float zacc;
    __shared__ int   cacc[8];
    int tid = threadIdx.x;
    for (int i = tid; i < 8192; i += 256) lrw[i & 7][i >> 3] = rw[i];
    if (tid < 8) { pacc[tid] = 0.f; cacc[tid] = 0; }
    if (tid == 0) zacc = 0.f;
    __syncthreads();
    int lane = tid & 63, wv = tid >> 6;
    for (int t = blockIdx.x * 4 + wv; t < TK; t += 1024) {
        float part[8];
#pragma unroll
        for (int e = 0; e < 8; ++e) part[e] = 0.f;
        const float* xr = x + ((size_t)t << 10);
        for (int j = 0; j < 16; ++j) {
            float xv = xr[j * 64 + lane];
#pragma unroll
            for (int e = 0; e < 8; ++e) part[e] += xv * lrw[e][j * 64 + lane];
        }
#pragma unroll
        for (int e = 0; e < 8; ++e) {
            float v = part[e];
            v += __shfl_xor(v, 32); v += __shfl_xor(v, 16); v += __shfl_xor(v, 8);
            v += __shfl_xor(v, 4);  v += __shfl_xor(v, 2);  v += __shfl_xor(v, 1);
            part[e] = v;
        }
        if (lane == 0) {
            float m = part[0];
#pragma unroll
            for (int e = 1; e < 8; ++e) m = fmaxf(m, part[e]);
            float pe[8]; float se = 0.f;
#pragma unroll
            for (int e = 0; e < 8; ++e) { pe[e] = __expf(part[e] - m); se += pe[e]; }
            float inv = 1.0f / se;
            int i0 = 0; float v0 = part[0];
#pragma unroll
            for (int e = 1; e < 8; ++e) if (part[e] > v0) { v0 = part[e]; i0 = e; }
            int i1 = -1; float v1 = -1e30f;
#pragma unroll
            for (int e = 0; e < 8; ++e) if (e != i0 && part[e] > v1) { v1 = part[e]; i1 = e; }
            float p0 = pe[i0] * inv, p1 = pe[i1] * inv;
            float wn = 1.0f / (p0 + p1);
            tk_idx[t * 2 + 0] = i0; tk_idx[t * 2 + 1] = i1;
            tk_w[t * 2 + 0] = p0 * wn; tk_w[t * 2 + 1] = p1 * wn;
            float z = __logf(se) + m;
            atomicAdd(&zacc, z * z);
#pragma unroll
            for (int e = 0; e < 8; ++e) atomicAdd(&pacc[e], pe[e] * inv);
            atomicAdd(&cacc[i0], 1);
            atomicAdd(&cacc[i1], 1);
        }
    }
    __syncthreads();
    if (tid < 8) { atomicAdd(&counts[tid], cacc[tid]); atomicAdd(&probsum[tid], pacc[tid]); }
    if (tid == 0) atomicAdd(z2sum, zacc);
}

// ---------------- finalize: aux outputs, bases, tile map (parallel fill) ----------------
__global__ __launch_bounds__(256) void finalize_kernel(const int* __restrict__ counts,
                                const float* __restrict__ probsum,
                                const float* __restrict__ z2sum, int* __restrict__ base,
                                int* __restrict__ cursor, int* __restrict__ tile_e,
                                int* __restrict__ tile_r0, int* __restrict__ tile_rc,
                                int* __restrict__ num_tiles, float* __restrict__ out_aux) {
    __shared__ int scnt[8], sbase[8], tstart[9];
    int tid = threadIdx.x;
    if (tid == 0) {
        int b = 0, ts = 0; float lbl = 0.f;
        for (int e = 0; e < 8; ++e) {
            int c = counts[e];
            scnt[e] = c; sbase[e] = b; tstart[e] = ts;
            base[e] = b; cursor[e] = b;
            float load = (float)c / 16384.0f;
            out_aux[e] = load;
            lbl += (load * 4.0f) * (probsum[e] / 8192.0f);
            b += c; ts += (c + 127) >> 7;
        }
        tstart[8] = ts;
        *num_tiles = ts;
        out_aux[8] = 0.01f * lbl;
        out_aux[9] = 0.001f * (*z2sum / 8192.0f);
    }
    __syncthreads();
    int nt = tstart[8];
    for (int u = tid; u < nt; u += 256) {
        int e = 0;
#pragma unroll
        for (int k = 0; k < 8; ++k) if (u >= tstart[k + 1]) e = k + 1;
        int i = u - tstart[e];
        int rem = scnt[e] - (i << 7);
        tile_e[u] = e;
        tile_r0[u] = sbase[e] + (i << 7);
        tile_rc[u] = rem < 128 ? rem : 128;
    }
}

// ---------------- scatter: permutation via hierarchical atomics ----------------
__global__ __launch_bounds__(256) void scatter_kernel(const int* __restrict__ tk_idx,
                                                      const float* __restrict__ tk_w,
                                                      int* __restrict__ cursor,
                                                      int* __restrict__ row_token,
                                                      float* __restrict__ row_w,
                                                      int* __restrict__ pos) {
    __shared__ int hist[8];
    __shared__ int lbase[8];
    int tid = threadIdx.x;
    if (tid < 8) hist[tid] = 0;
    __syncthreads();
    int idx = blockIdx.x * 256 + tid;
    int e = tk_idx[idx];
    atomicAdd(&hist[e], 1);
    __syncthreads();
    if (tid < 8) lbase[tid] = atomicAdd(&cursor[tid], hist[tid]);
    __syncthreads();
    if (tid < 8) hist[tid] = 0;
    __syncthreads();
    int r = lbase[e] + atomicAdd(&hist[e], 1);
    row_token[r] = idx >> 1;
    row_w[r] = tk_w[idx];
    pos[idx] = r;
}

// ---------------- gather x rows -> bf16 permuted matrix ----------------
__global__ __launch_bounds__(256) void gather_kernel(const float* __restrict__ x,
                                                     const int* __restrict__ row_token,
                                                     unsigned short* __restrict__ xp) {
    int idx = blockIdx.x * 256 + threadIdx.x;      // TR*128 total
    int r = idx >> 7, j = idx & 127;
    int t = row_token[r];
    const float4* s = (const float4*)(x + ((size_t)t << 10) + (j << 3));
    float4 v0 = s[0], v1 = s[1];
    s16x8 o;
    o[0] = (short)f2bf(v0.x); o[1] = (short)f2bf(v0.y);
    o[2] = (short)f2bf(v0.z); o[3] = (short)f2bf(v0.w);
    o[4] = (short)f2bf(v1.x); o[5] = (short)f2bf(v1.y);
    o[6] = (short)f2bf(v1.z); o[7] = (short)f2bf(v1.w);
    *(s16x8*)(xp + ((size_t)r << 10) + (j << 3)) = o;
}

// ---------------- fused grouped GEMM1 (persistent + work-stealing) ----------------
__global__ __launch_bounds__(256, 2) void gemm1_kernel(const short* __restrict__ Xp,
                                                       const short* __restrict__ W1t,
                                                       const short* __restrict__ W2t,
                                                       unsigned short* __restrict__ H,
                                                       const int* __restrict__ tile_e,
                                                       const int* __restrict__ tile_r0,
                                                       const int* __restrict__ tile_rc,
                                                       const int* __restrict__ num_tiles,
                                                       int* __restrict__ gcur) {
    __shared__ __align__(16) short As[128 * 64];
    __shared__ __align__(16) short B1s[128 * 64];
    __shared__ __align__(16) short B2s[128 * 64];
    __shared__ int s_t;

    int tid = threadIdx.x, lane = tid & 63, wv = tid >> 6;
    int wm = wv >> 1, wn = wv & 1;
    int swz = (lane & 7) ^ ((lane >> 3) & 7);          // global chunk permutation
    short* asw = As  + wv * 32 * 64;
    short* b1w = B1s + wv * 32 * 64;
    short* b2w = B2s + wv * 32 * 64;

    int total = *num_tiles * 24;
    while (true) {
        __syncthreads();
        if (tid == 0) s_t = atomicAdd(gcur, 1);
        __syncthreads();
        int t = s_t;
        if (t >= total) break;
        int mt = t / 24, ntile = t - mt * 24;
        int e = tile_e[mt], m0 = tile_r0[mt], rows = tile_rc[mt];
        int n0 = ntile << 7;

        f32x4 z4 = {0.f, 0.f, 0.f, 0.f};
        f32x4 acc1[4][4], acc2[4][4];
#pragma unroll
        for (int a = 0; a < 4; ++a)
#pragma unroll
            for (int b = 0; b < 4; ++b) { acc1[a][b] = z4; acc2[a][b] = z4; }

        const short* ab  = Xp  + (size_t)(m0 + wv * 32 + (lane >> 3)) * 1024 + swz * 8;
        const short* b1b = W1t + ((size_t)e * 3072 + n0 + wv * 32 + (lane >> 3)) * 1024 + swz * 8;
        const short* b2b = W2t + ((size_t)e * 3072 + n0 + wv * 32 + (lane >> 3)) * 1024 + swz * 8;

        for (int k0 = 0; k0 < 1024; k0 += 64) {
#pragma unroll
            for (int i = 0; i < 4; ++i) {
                async16(ab  + (size_t)i * 8 * 1024 + k0, asw + i * 8 * 64);
                async16(b1b + (size_t)i * 8 * 1024 + k0, b1w + i * 8 * 64);
                async16(b2b + (size_t)i * 8 * 1024 + k0, b2w + i * 8 * 64);
            }
            __syncthreads();
#pragma unroll
            for (int kk = 0; kk < 2; ++kk) {
                bf16x8 af[4];
#pragma unroll
                for (int mi = 0; mi < 4; ++mi) {
                    int ar = wm * 64 + mi * 16 + (lane & 15);
                    int ac = (kk * 4 + (lane >> 4)) ^ (ar & 7);
                    af[mi] = *(const bf16x8*)&As[ar * 64 + ac * 8];
                }
#pragma unroll
                for (int ni = 0; ni < 4; ++ni) {
                    int br = wn * 64 + ni * 16 + (lane & 15);
                    int bc = (kk * 4 + (lane >> 4)) ^ (br & 7);
                    bf16x8 b1 = *(const bf16x8*)&B1s[br * 64 + bc * 8];
                    bf16x8 b2 = *(const bf16x8*)&B2s[br * 64 + bc * 8];
#pragma unroll
                    for (int mi = 0; mi < 4; ++mi) {
                        acc1[mi][ni] = __builtin_amdgcn_mfma_f32_16x16x32_bf16(af[mi], b1, acc1[mi][ni], 0, 0, 0);
                        acc2[mi][ni] = __builtin_amdgcn_mfma_f32_16x16x32_bf16(af[mi], b2, acc2[mi][ni], 0, 0, 0);
                    }
                }
            }
            __syncthreads();
        }
#pragma unroll
        for (int mi = 0; mi < 4; ++mi) {
#pragma unroll
            for (int i = 0; i < 4; ++i) {
                int rl = wm * 64 + mi * 16 + (lane >> 4) * 4 + i;
                if (rl < rows) {
                    size_t rowoff = (size_t)(m0 + rl) * 3072 + n0;
#pragma unroll
                    for (int ni = 0; ni < 4; ++ni) {
                        int cl = wn * 64 + ni * 16 + (lane & 15);
                        float c1 = acc1[mi][ni][i];
                        float c2 = acc2[mi][ni][i];
                        float hv = c1 * c2 / (1.0f + __expf(-c1));   // silu(c1)*c2
                        H[rowoff + cl] = f2bf(hv);
                    }
                }
            }
        }
    }
}

// ---------------- grouped GEMM2 (persistent + work-stealing) ----------------
__global__ __launch_bounds__(256, 2) void gemm2_kernel(const short* __restrict__ Hs,
                                                       const short* __restrict__ W3t,
                                                       const float* __restrict__ row_w,
                                                       unsigned short* __restrict__ OR,
                                                       const int* __restrict__ tile_e,
                                                       const int* __restrict__ tile_r0,
                                                       const int* __restrict__ tile_rc,
                                                       const int* __restrict__ num_tiles,
                                                       int* __restrict__ gcur) {
    __shared__ __align__(16) short As[128 * 64];
    __shared__ __align__(16) short Bs[128 * 64];
    __shared__ int s_t;

    int tid = threadIdx.x, lane = tid & 63, wv = tid >> 6;
    int wm = wv >> 1, wn = wv & 1;
    int swz = (lane & 7) ^ ((lane >> 3) & 7);
    short* asw = As + wv * 32 * 64;
    short* bsw = Bs + wv * 32 * 64;

    int total = *num_tiles * 8;
    while (true) {
        __syncthreads();
        if (tid == 0) s_t = atomicAdd(gcur, 1);
        __syncthreads();
        int t = s_t;
        if (t >= total) break;
        int mt = t >> 3, ntile = t & 7;
        int e = tile_e[mt], m0 = tile_r0[mt], rows = tile_rc[mt];
        int n0 = ntile << 7;

        f32x4 z4 = {0.f, 0.f, 0.f, 0.f};
        f32x4 acc[4][4];
#pragma unroll
        for (int a = 0; a < 4; ++a)
#pragma unroll
            for (int b = 0; b < 4; ++b) acc[a][b] = z4;

        const short* ab = Hs  + (size_t)(m0 + wv * 32 + (lane >> 3)) * 3072 + swz * 8;
        const short* bb = W3t + ((size_t)e * 1024 + n0 + wv * 32 + (lane >> 3)) * 3072 + swz * 8;

        for (int k0 = 0; k0 < 3072; k0 += 64) {
#pragma unroll
            for (int i = 0; i < 4; ++i) {
                async16(ab + (size_t)i * 8 * 3072 + k0, asw + i * 8 * 64);
                async16(bb + (size_t)i * 8 * 3072 + k0, bsw + i * 8 * 64);
            }
            __syncthreads();
#pragma unroll
            for (int kk = 0; kk < 2; ++kk) {
                bf16x8 af[4];
#pragma unroll
                for (int mi = 0; mi < 4; ++mi) {
                    int ar = wm * 64 + mi * 16 + (lane & 15);
                    int ac = (kk * 4 + (lane >> 4)) ^ (ar & 7);
                    af[mi] = *(const bf16x8*)&As[ar * 64 + ac * 8];
                }
#pragma unroll
                for (int ni = 0; ni < 4; ++ni) {
                    int br = wn * 64 + ni * 16 + (lane & 15);
                    int bc = (kk * 4 + (lane >> 4)) ^ (br & 7);
                    bf16x8 bfr = *(const bf16x8*)&Bs[br * 64 + bc * 8];
#pragma unroll
                    for (int mi = 0; mi < 4; ++mi)
                        acc[mi][ni] = __builtin_amdgcn_mfma_f32_16x16x32_bf16(af[mi], bfr, acc[mi][ni], 0, 0, 0);
                }
            }
            __syncthreads();
        }
#pragma unroll
        for (int mi = 0; mi < 4; ++mi) {
#pragma unroll
            for (int i = 0; i < 4; ++i) {
                int rl = wm * 64 + mi * 16 + (lane >> 4) * 4 + i;
                if (rl < rows) {
                    float sc = row_w[m0 + rl];
                    size_t rowoff = (size_t)(m0 + rl) * 1024 + n0;
#pragma unroll
                    for (int ni = 0; ni < 4; ++ni) {
                        int cl = wn * 64 + ni * 16 + (lane & 15);
                        OR[rowoff + cl] = f2bf(acc[mi][ni][i] * sc);
                    }
                }
            }
        }
    }
}

// ---------------- combine: out[t] = rows[pos0] + rows[pos1] (already weighted) ----------------
__global__ __launch_bounds__(256) void combine_kernel(const unsigned short* __restrict__ rows,
                                                      const int* __restrict__ pos,
                                                      float* __restrict__ out) {
    int idx = blockIdx.x * 256 + threadIdx.x;      // TK*128 total
    int t = idx >> 7, j = idx & 127;
    int p0 = pos[t * 2 + 0], p1 = pos[t * 2 + 1];
    s16x8 a = *(const s16x8*)(rows + ((size_t)p0 << 10) + (j << 3));
    s16x8 b = *(const s16x8*)(rows + ((size_t)p1 << 10) + (j << 3));
    float4 o0, o1;
    o0.x = bf2f((unsigned short)a[0]) + bf2f((unsigned short)b[0]);
    o0.y = bf2f((unsigned short)a[1]) + bf2f((unsigned short)b[1]);
    o0.z = bf2f((unsigned short)a[2]) + bf2f((unsigned short)b[2]);
    o0.w = bf2f((unsigned short)a[3]) + bf2f((unsigned short)b[3]);
    o1.x = bf2f((unsigned short)a[4]) + bf2f((unsigned short)b[4]);
    o1.y = bf2f((unsigned short)a[5]) + bf2f((unsigned short)b[5]);
    o1.z = bf2f((unsigned short)a[6]) + bf2f((unsigned short)b[6]);
    o1.w = bf2f((unsigned short)a[7]) + bf2f((unsigned short)b[7]);
    float* dst = out + ((size_t)t << 10) + (j << 3);
    ((float4*)dst)[0] = o0;
    ((float4*)dst)[1] = o1;
}

// ---------------- launch ----------------
extern "C" void kernel_launch(void* const* d_in, const int* in_sizes, int n_in,
                              void* d_out, int out_size, void* d_ws, size_t ws_size,
                              hipStream_t stream) {
    const float* x  = (const float*)d_in[0];
    const float* rw = (const float*)d_in[1];
    const float* w1 = (const float*)d_in[2];
    const float* w2 = (const float*)d_in[3];
    const float* w3 = (const float*)d_in[4];
    float* out = (float*)d_out;
    char* ws = (char*)d_ws;

    // ws layout (bytes)
    int*   counts    = (int*)(ws + 0);
    int*   cursor    = (int*)(ws + 32);
    float* probsum   = (float*)(ws + 64);
    float* z2sum     = (float*)(ws + 96);
    int*   num_tiles = (int*)(ws + 100);
    int*   gcur1     = (int*)(ws + 104);
    int*   gcur2     = (int*)(ws + 108);
    int*   base      = (int*)(ws + 128);
    int*   tile_e    = (int*)(ws + 256);
    int*   tile_r0   = (int*)(ws + 1024);
    int*   tile_rc   = (int*)(ws + 1792);
    int*   row_token = (int*)(ws + 2560);
    float* row_w     = (float*)(ws + 68096);
    int*   pos       = (int*)(ws + 133632);
    int*   tk_idx    = (int*)(ws + 199168);
    float* tk_w      = (float*)(ws + 264704);
    unsigned short* xp   = (unsigned short*)(ws + 330240);     // [TRP][DD]
    unsigned short* w1t  = (unsigned short*)(ws + 34146816);   // [E][II][DD]
    unsigned short* w2t  = (unsigned short*)(ws + 84478464);
    unsigned short* w3t  = (unsigned short*)(ws + 134810112);  // [E][DD][II]
    unsigned short* h    = (unsigned short*)(ws + 185141760);  // [TRP][II]
    unsigned short* orows= (unsigned short*)(ws + 286591488);  // [TR][DD]

    init_kernel<<<dim3(1), dim3(256), 0, stream>>>((int*)ws);
    transpose_all<<<dim3(768, 24), dim3(256), 0, stream>>>(w1, w2, w3, w1t, w2t, w3t);
    router_kernel<<<dim3(256), dim3(256), 0, stream>>>(x, rw, counts, probsum, z2sum, tk_idx, tk_w);
    finalize_kernel<<<dim3(1), dim3(256), 0, stream>>>(counts, probsum, z2sum, base, cursor,
                                                       tile_e, tile_r0, tile_rc, num_tiles,
                                                       out + (size_t)TK * DD);
    scatter_kernel<<<dim3(64), dim3(256), 0, stream>>>(tk_idx, tk_w, cursor, row_token, row_w, pos);
    gather_kernel<<<dim3(TR * DD / 8 / 256), dim3(256), 0, stream>>>(x, row_token, xp);
    gemm1_kernel<<<dim3(G1_BLOCKS), dim3(256), 0, stream>>>(
        (const short*)xp, (const short*)w1t, (const short*)w2t, h,
        tile_e, tile_r0, tile_rc, num_tiles, gcur1);
    gemm2_kernel<<<dim3(G2_BLOCKS), dim3(256), 0, stream>>>(
        (const short*)h, (const short*)w3t, row_w, orows,
        tile_e, tile_r0, tile_rc, num_tiles, gcur2);
    combine_kernel<<<dim3(TK * DD / 8 / 256), dim3(256), 0, stream>>>(orows, pos, out);
}